// Round 7
// baseline (45.915 us; speedup 1.0000x reference)
//
#include <hip/hip_runtime.h>
#include <math.h>

// Problem constants (from reference): B=8, N=512, T=8192, D=256.
#define BB 8
#define NN 512
#define TT 8192
#define DD 256

#define THREADS 256
#define BLOCKS  (BB * 256)   // 2048: bid = b*256 + rblk; all resident (8/CU)

// clang ext-vector: __builtin_nontemporal_store requires a raw vector type.
typedef float v4f __attribute__((ext_vector_type(4)));

// ---------------------------------------------------------------------------
// ONE fused kernel. Block bid = (b, rblk):
//   1) LDS scan of dur[b,:] (512 ints, 2/thread, Hillis-Steele on 256 pairs)
//      -> s_end[0..512] (segment starts; s_end[NN]=T) + per-segment coverage.
//   2) threads 0..31: binary-search seg for frames t0..t0+31, write positions.
//   3) out chunk: frames t0 = rblk*32 .. +31  (32 KiB, linear in bid)
//   4) weights rows n0 = rblk*2, n0+1          (64 KiB, linear in bid)
//      -> NO seg reads: row n is 1 exactly on [start(+1 if uncovered), end).
//
// fp32 boundary subtlety (verified round 2): at t == start, t - c == -dur/2
// exactly; reference adds 1e-6f. For dur/2 >= 32 the half-ULP exceeds 1e-6 so
// the sum rounds back to dur/2 -> that start frame is covered by NO segment
// (weights column all zero, out row zero, positions = t).
// ---------------------------------------------------------------------------
__global__ void __launch_bounds__(THREADS)
fused_kernel(const float* __restrict__ x,
             const int* __restrict__ dur,
             float* __restrict__ positions,
             float* __restrict__ outp,
             float* __restrict__ w) {
    __shared__ int s_end[NN + 1];
    __shared__ unsigned char s_cov[NN];
    __shared__ int s_ps[THREADS];
    __shared__ int seg_blk[32];

    const int bid  = blockIdx.x;
    const int b    = bid >> 8;
    const int rblk = bid & 255;
    const int tid  = threadIdx.x;

    // ---- 1) scan: each thread owns durations 2*tid, 2*tid+1 ----
    const int2 dp = *(const int2*)(dur + b * NN + 2 * tid);
    s_ps[tid] = dp.x + dp.y;
    for (int off = 1; off < THREADS; off <<= 1) {
        __syncthreads();
        const int v = (tid >= off) ? s_ps[tid - off] : 0;
        __syncthreads();
        s_ps[tid] += v;
    }
    const int S = s_ps[tid];                 // inclusive pair-sum (own element)
    if (tid == 0) s_end[0] = 0;
    s_end[2 * tid + 1] = S - dp.y;           // start of segment 2*tid+1
    s_end[2 * tid + 2] = S;                  // start of segment 2*tid+2 (or T)
    {
        const float h0 = 0.5f * (float)dp.x;
        const float h1 = 0.5f * (float)dp.y;
        s_cov[2 * tid]     = (fabsf(1e-6f - h0) < h0) ? 1 : 0;
        s_cov[2 * tid + 1] = (fabsf(1e-6f - h1) < h1) ? 1 : 0;
    }
    __syncthreads();

    // ---- 2) per-frame segment lookup for this block's 32 out-frames ----
    const int t0 = rblk * 32;
    if (tid < 32) {
        const int t = t0 + tid;
        int lo = 0, hi = NN - 1;             // find lo: s_end[lo] <= t < s_end[lo+1]
        while (lo < hi) {
            const int mid = (lo + hi) >> 1;
            if (t < s_end[mid + 1]) hi = mid; else lo = mid + 1;
        }
        const int st  = s_end[lo];
        const bool unc = (t == st) && !s_cov[lo];
        seg_blk[tid] = unc ? -1 : lo;
        positions[b * TT + t] = unc ? (float)t : (float)(t - st);
    }

    // weights run bounds for this block's two rows (uniform LDS broadcasts)
    const int n0  = rblk * 2;
    const int rs0 = s_end[n0]     + (s_cov[n0]     ? 0 : 1);
    const int re0 = s_end[n0 + 1];
    const int rs1 = s_end[n0 + 1] + (s_cov[n0 + 1] ? 0 : 1);
    const int re1 = s_end[n0 + 2];
    __syncthreads();                         // seg_blk ready

    // ---- 3) out: 8 iters x 1 KiB/wave; frame uniform per wave-instruction ----
    #pragma unroll
    for (int k = 0; k < 8; ++k) {
        const int idx = k * 256 + tid;       // float4 index in 32 KiB chunk
        const int f   = idx >> 6;            // frame 0..31 (uniform per wave)
        const int d4  = (idx & 63) << 2;
        const int sg  = seg_blk[f];
        v4f v = (v4f)(0.0f);
        if (sg >= 0)
            v = *(const v4f*)(x + (((size_t)b * NN + sg) * DD + d4));
        __builtin_nontemporal_store(v,
            (v4f*)(outp + (((size_t)b * TT + (t0 + f)) * DD + d4)));
    }

    // ---- 4) weights: 16 iters x 1 KiB/wave, zero reads, linear 64 KiB ----
    #pragma unroll
    for (int k = 0; k < 16; ++k) {
        const int r  = k >> 3;               // 0 or 1: which of the two rows
        const int n  = n0 + r;
        const int rs = r ? rs1 : rs0;
        const int re = r ? re1 : re0;
        const int t  = ((k & 7) << 10) + (tid << 2);
        v4f o;
        o.x = (t     >= rs && t     < re) ? 1.0f : 0.0f;
        o.y = (t + 1 >= rs && t + 1 < re) ? 1.0f : 0.0f;
        o.z = (t + 2 >= rs && t + 2 < re) ? 1.0f : 0.0f;
        o.w = (t + 3 >= rs && t + 3 < re) ? 1.0f : 0.0f;
        __builtin_nontemporal_store(o,
            (v4f*)(w + ((((size_t)b * NN + n) << 13) + t)));
    }
}

extern "C" void kernel_launch(void* const* d_in, const int* in_sizes, int n_in,
                              void* d_out, int out_size, void* d_ws, size_t ws_size,
                              hipStream_t stream) {
    const float* x  = (const float*)d_in[0];
    const int* dur  = (const int*)d_in[1];

    // Output layout: positions [B,T] | out [B,T,D] | weights [B,N,T]
    float* pos  = (float*)d_out;
    float* outp = pos + (size_t)BB * TT;
    float* w    = outp + (size_t)BB * TT * DD;

    fused_kernel<<<BLOCKS, THREADS, 0, stream>>>(x, dur, pos, outp, w);
}

// Round 8
// 43.461 us; speedup vs baseline: 1.0565x; 1.0565x over previous
//
#include <hip/hip_runtime.h>
#include <math.h>

// Problem constants (from reference): B=8, N=512, T=8192, D=256.
#define BB 8
#define NN 512
#define TT 8192
#define DD 256

#define THREADS 256
#define BLOCKS  256   // 1 block/CU. Few, long, LINEAR write streams (fill-kernel shape).

// clang ext-vector: __builtin_nontemporal_store requires a raw vector type.
typedef float v4f __attribute__((ext_vector_type(4)));

// ---------------------------------------------------------------------------
// ONE fused kernel, 256 blocks = (b, sub): b = batch, sub = 1/32 of batch.
//   1) LDS pair-scan of dur[b,:] -> s_end[0..512] (starts; s_end[NN]=T), s_cov
//   2) frames f0..f0+255 (f0 = sub*256): binary search -> seg_blk, positions
//   3) out chunk: 256 frames = 256 KiB, ONE linear sweep
//   4) weights rows sub*16..+15: 16 x 32 KiB = 512 KiB linear, ZERO reads
//      (row n is 1 exactly on [start(+1 if uncovered), end))
//
// Round-7 lesson: 2048+ blocks x 3 regions = ~6k concurrent HBM write
// streams ran at ~4.7 TB/s; the 6.9 TB/s fill kernel uses ~10% occupancy and
// a few hundred linear streams. This kernel copies that shape.
//
// fp32 boundary subtlety (verified round 2): at t == start, t - c == -dur/2
// exactly; reference adds 1e-6f. For dur/2 >= 32 the half-ULP exceeds 1e-6 so
// the sum rounds back to dur/2 -> that start frame is covered by NO segment
// (weights column all zero, out row zero, positions = t).
// ---------------------------------------------------------------------------
__global__ void __launch_bounds__(THREADS)
fused_kernel(const float* __restrict__ x,
             const int* __restrict__ dur,
             float* __restrict__ positions,
             float* __restrict__ outp,
             float* __restrict__ w) {
    __shared__ int s_end[NN + 1];
    __shared__ unsigned char s_cov[NN];
    __shared__ int s_ps[THREADS];
    __shared__ short seg_blk[256];

    const int bid = blockIdx.x;
    const int b   = bid >> 5;
    const int sub = bid & 31;
    const int tid = threadIdx.x;

    // ---- 1) scan: thread owns durations 2*tid, 2*tid+1 ----
    const int2 dp = *(const int2*)(dur + b * NN + 2 * tid);
    s_ps[tid] = dp.x + dp.y;
    for (int off = 1; off < THREADS; off <<= 1) {
        __syncthreads();
        const int v = (tid >= off) ? s_ps[tid - off] : 0;
        __syncthreads();
        s_ps[tid] += v;
    }
    const int S = s_ps[tid];                 // inclusive pair-sum
    if (tid == 0) s_end[0] = 0;
    s_end[2 * tid + 1] = S - dp.y;
    s_end[2 * tid + 2] = S;
    {
        const float h0 = 0.5f * (float)dp.x;
        const float h1 = 0.5f * (float)dp.y;
        s_cov[2 * tid]     = (fabsf(1e-6f - h0) < h0) ? 1 : 0;
        s_cov[2 * tid + 1] = (fabsf(1e-6f - h1) < h1) ? 1 : 0;
    }
    __syncthreads();

    // ---- 2) segment lookup for this block's 256 frames (1/thread) ----
    const int f0 = sub * 256;
    {
        const int t = f0 + tid;
        int lo = 0, hi = NN - 1;             // find lo: s_end[lo] <= t < s_end[lo+1]
        while (lo < hi) {
            const int mid = (lo + hi) >> 1;
            if (t < s_end[mid + 1]) hi = mid; else lo = mid + 1;
        }
        const int st  = s_end[lo];
        const bool unc = (t == st) && !s_cov[lo];
        seg_blk[tid] = (short)(unc ? -1 : lo);
        positions[b * TT + t] = unc ? (float)t : (float)(t - st);
    }
    __syncthreads();

    // ---- 3) out: 256 frames, 64 iters x 1 KiB/wave, linear 256 KiB ----
    float* oc = outp + ((size_t)b * TT + f0) * DD;
    #pragma unroll 4
    for (int k = 0; k < 64; ++k) {
        const int idx = k * THREADS + tid;   // float4 index in chunk
        const int f   = idx >> 6;            // frame 0..255 (uniform per wave)
        const int d4  = (idx & 63) << 2;
        const int sg  = seg_blk[f];
        v4f v = (v4f)(0.0f);
        if (sg >= 0)
            v = *(const v4f*)(x + (((size_t)b * NN + sg) * DD + d4));
        __builtin_nontemporal_store(v, (v4f*)(oc + ((size_t)idx << 2)));
    }

    // ---- 4) weights: 16 rows x 32 KiB, zero reads, linear 512 KiB ----
    const int n0 = sub * 16;
    for (int r = 0; r < 16; ++r) {
        const int n  = n0 + r;
        const int rs = s_end[n] + (s_cov[n] ? 0 : 1);
        const int re = s_end[n + 1];
        float* wrow = w + (((size_t)b * NN + n) << 13);
        #pragma unroll
        for (int k = 0; k < 8; ++k) {
            const int t = (k * THREADS + tid) << 2;
            v4f o;
            o.x = (t     >= rs && t     < re) ? 1.0f : 0.0f;
            o.y = (t + 1 >= rs && t + 1 < re) ? 1.0f : 0.0f;
            o.z = (t + 2 >= rs && t + 2 < re) ? 1.0f : 0.0f;
            o.w = (t + 3 >= rs && t + 3 < re) ? 1.0f : 0.0f;
            __builtin_nontemporal_store(o, (v4f*)(wrow + t));
        }
    }
}

extern "C" void kernel_launch(void* const* d_in, const int* in_sizes, int n_in,
                              void* d_out, int out_size, void* d_ws, size_t ws_size,
                              hipStream_t stream) {
    const float* x  = (const float*)d_in[0];
    const int* dur  = (const int*)d_in[1];

    // Output layout: positions [B,T] | out [B,T,D] | weights [B,N,T]
    float* pos  = (float*)d_out;
    float* outp = pos + (size_t)BB * TT;
    float* w    = outp + (size_t)BB * TT * DD;

    fused_kernel<<<BLOCKS, THREADS, 0, stream>>>(x, dur, pos, outp, w);
}

// Round 9
// 42.225 us; speedup vs baseline: 1.0874x; 1.0293x over previous
//
#include <hip/hip_runtime.h>
#include <math.h>

// Problem constants (from reference): B=8, N=512, T=8192, D=256.
#define BB 8
#define NN 512
#define TT 8192
#define DD 256

#define THREADS 256
#define BLOCKS  256   // 1 block/CU, fill-kernel shape: few, long, linear streams

// clang ext-vector: __builtin_nontemporal_store requires a raw vector type.
typedef float v4f __attribute__((ext_vector_type(4)));

// ---------------------------------------------------------------------------
// Round-9 structure: weights' 134 MB of ZEROS go through hipMemsetAsync
// (the rocclr fillBufferAligned path measured at 6.9 TB/s on these very
// buffers); this kernel only writes out (67 MB), positions (0.26 MB), and
// the ~65k weight ONES (runs [rs,re) per row — zero reads needed).
//
// Block (b, sub): sub = 1/32 of a batch.
//   1) LDS pair-scan of dur[b,:] -> s_end[0..512] (starts; s_end[NN]=T), s_cov
//   2) frames f0..f0+255: binary search -> seg_blk, positions
//   3) out chunk: 256 frames = 256 KiB, one linear sweep (gather x from L2)
//   4) ones for rows n0..n0+15: wrow[rs..re) = 1.0f (re-rs ~ dur, <= ~270)
//
// fp32 boundary subtlety (verified round 2): at t == start, t - c == -dur/2
// exactly; reference adds 1e-6f. For dur/2 >= 32 the half-ULP exceeds 1e-6 so
// the sum rounds back to dur/2 -> that start frame is covered by NO segment
// (weights column all zero, out row zero, positions = t). Hence rs gets +1
// when uncovered.
// ---------------------------------------------------------------------------
__global__ void __launch_bounds__(THREADS)
fused_kernel(const float* __restrict__ x,
             const int* __restrict__ dur,
             float* __restrict__ positions,
             float* __restrict__ outp,
             float* __restrict__ w) {
    __shared__ int s_end[NN + 1];
    __shared__ unsigned char s_cov[NN];
    __shared__ int s_ps[THREADS];
    __shared__ short seg_blk[256];

    const int bid = blockIdx.x;
    const int b   = bid >> 5;
    const int sub = bid & 31;
    const int tid = threadIdx.x;

    // ---- 1) scan: thread owns durations 2*tid, 2*tid+1 ----
    const int2 dp = *(const int2*)(dur + b * NN + 2 * tid);
    s_ps[tid] = dp.x + dp.y;
    for (int off = 1; off < THREADS; off <<= 1) {
        __syncthreads();
        const int v = (tid >= off) ? s_ps[tid - off] : 0;
        __syncthreads();
        s_ps[tid] += v;
    }
    const int S = s_ps[tid];                 // inclusive pair-sum
    if (tid == 0) s_end[0] = 0;
    s_end[2 * tid + 1] = S - dp.y;
    s_end[2 * tid + 2] = S;
    {
        const float h0 = 0.5f * (float)dp.x;
        const float h1 = 0.5f * (float)dp.y;
        s_cov[2 * tid]     = (fabsf(1e-6f - h0) < h0) ? 1 : 0;
        s_cov[2 * tid + 1] = (fabsf(1e-6f - h1) < h1) ? 1 : 0;
    }
    __syncthreads();

    // ---- 2) segment lookup for this block's 256 frames (1/thread) ----
    const int f0 = sub * 256;
    {
        const int t = f0 + tid;
        int lo = 0, hi = NN - 1;             // find lo: s_end[lo] <= t < s_end[lo+1]
        while (lo < hi) {
            const int mid = (lo + hi) >> 1;
            if (t < s_end[mid + 1]) hi = mid; else lo = mid + 1;
        }
        const int st  = s_end[lo];
        const bool unc = (t == st) && !s_cov[lo];
        seg_blk[tid] = (short)(unc ? -1 : lo);
        positions[b * TT + t] = unc ? (float)t : (float)(t - st);
    }
    __syncthreads();

    // ---- 3) out: 256 frames, 64 iters x 1 KiB/wave, linear 256 KiB ----
    float* oc = outp + ((size_t)b * TT + f0) * DD;
    #pragma unroll 4
    for (int k = 0; k < 64; ++k) {
        const int idx = k * THREADS + tid;   // float4 index in chunk
        const int f   = idx >> 6;            // frame 0..255 (uniform per wave)
        const int d4  = (idx & 63) << 2;
        const int sg  = seg_blk[f];
        v4f v = (v4f)(0.0f);
        if (sg >= 0)
            v = *(const v4f*)(x + (((size_t)b * NN + sg) * DD + d4));
        __builtin_nontemporal_store(v, (v4f*)(oc + ((size_t)idx << 2)));
    }

    // ---- 4) weight ones: rows n0..n0+15, write 1.0f on [rs, re) ----
    const int n0 = sub * 16;
    for (int r = 0; r < 16; ++r) {
        const int n  = n0 + r;
        const int rs = s_end[n] + (s_cov[n] ? 0 : 1);
        const int re = s_end[n + 1];
        float* wrow = w + (((size_t)b * NN + n) << 13);
        for (int t = rs + tid; t < re; t += THREADS)
            wrow[t] = 1.0f;
    }
}

extern "C" void kernel_launch(void* const* d_in, const int* in_sizes, int n_in,
                              void* d_out, int out_size, void* d_ws, size_t ws_size,
                              hipStream_t stream) {
    const float* x  = (const float*)d_in[0];
    const int* dur  = (const int*)d_in[1];

    // Output layout: positions [B,T] | out [B,T,D] | weights [B,N,T]
    float* pos  = (float*)d_out;
    float* outp = pos + (size_t)BB * TT;
    float* w    = outp + (size_t)BB * TT * DD;

    // Zeros for weights via the rocclr fill path (6.9 TB/s measured on this
    // chip for these buffers). Stream order makes the kernel's ones-writes
    // safely follow it.
    hipMemsetAsync(w, 0, (size_t)BB * NN * TT * sizeof(float), stream);
    fused_kernel<<<BLOCKS, THREADS, 0, stream>>>(x, dur, pos, outp, w);
}

// Round 10
// 39.919 us; speedup vs baseline: 1.1502x; 1.0578x over previous
//
#include <hip/hip_runtime.h>
#include <math.h>

// Problem constants (from reference): B=8, N=512, T=8192, D=256.
#define BB 8
#define NN 512
#define TT 8192
#define DD 256

#define THREADS 256
#define BLOCKS  512        // (b, sub): 64 blocks/batch, 128 frames each; 2/CU
#define FRAMES  128        // frames per block
// Max distinct segments overlapping 128 consecutive frames: durations >= 8
// (except possibly the forced last row) -> <= ceil(128/8)+1 = 17; +1 slack.
#define MAXROWS 18

// clang ext-vector: __builtin_nontemporal_store requires a raw vector type.
typedef float v4f __attribute__((ext_vector_type(4)));

// ---------------------------------------------------------------------------
// Round-10 structure:
//   hipMemsetAsync zeros weights (134 MB) via the rocclr fill path.
//   Kernel (512 blocks): per block
//     1) LDS pair-scan of dur[b,:] -> s_end (starts), s_cov
//     2) frames f0..f0+127: binary search -> seg (lo), coverage, positions
//     3) STAGE the block's x rows (<=18 KiB) into LDS in one coalesced burst
//        -- round-9 lesson: vmem-load->store loops run at ~3.6 TB/s while
//        zero-read store loops run at ~6.4; so pay load latency ONCE here.
//     4) out: 128 KiB linear nt-store sweep fed from LDS (no vmem loads)
//     5) ones: weights rows sub*8..+7, w[rs..re)=1 (zero reads)
//
// fp32 boundary subtlety (verified round 2): at t == start, t - c == -dur/2
// exactly; reference adds 1e-6f. For dur/2 >= 32 the half-ULP exceeds 1e-6 so
// the sum rounds back to dur/2 -> that start frame is covered by NO segment
// (weights col zero, out row zero, positions = t). Hence rs+1 when uncovered.
// ---------------------------------------------------------------------------
__global__ void __launch_bounds__(THREADS)
fused_kernel(const float* __restrict__ x,
             const int* __restrict__ dur,
             float* __restrict__ positions,
             float* __restrict__ outp,
             float* __restrict__ w) {
    __shared__ int s_end[NN + 1];
    __shared__ unsigned char s_cov[NN];
    __shared__ int s_ps[THREADS];
    __shared__ short seg_blk[FRAMES];       // covered seg, or -1
    __shared__ int s_nlo, s_nhi;
    __shared__ float xs[(MAXROWS + 1) * DD];  // staged rows + 1 zero row

    const int bid = blockIdx.x;
    const int b   = bid >> 6;
    const int sub = bid & 63;
    const int tid = threadIdx.x;

    // ---- 1) scan: thread owns durations 2*tid, 2*tid+1 ----
    const int2 dp = *(const int2*)(dur + b * NN + 2 * tid);
    s_ps[tid] = dp.x + dp.y;
    for (int off = 1; off < THREADS; off <<= 1) {
        __syncthreads();
        const int v = (tid >= off) ? s_ps[tid - off] : 0;
        __syncthreads();
        s_ps[tid] += v;
    }
    const int S = s_ps[tid];                // inclusive pair-sum
    if (tid == 0) s_end[0] = 0;
    s_end[2 * tid + 1] = S - dp.y;
    s_end[2 * tid + 2] = S;
    {
        const float h0 = 0.5f * (float)dp.x;
        const float h1 = 0.5f * (float)dp.y;
        s_cov[2 * tid]     = (fabsf(1e-6f - h0) < h0) ? 1 : 0;
        s_cov[2 * tid + 1] = (fabsf(1e-6f - h1) < h1) ? 1 : 0;
    }
    __syncthreads();

    // ---- 2) segment lookup for this block's 128 frames ----
    const int f0 = sub * FRAMES;
    if (tid < FRAMES) {
        const int t = f0 + tid;
        int lo = 0, hi = NN - 1;            // find lo: s_end[lo] <= t < s_end[lo+1]
        while (lo < hi) {
            const int mid = (lo + hi) >> 1;
            if (t < s_end[mid + 1]) hi = mid; else lo = mid + 1;
        }
        const int st   = s_end[lo];
        const bool unc = (t == st) && !s_cov[lo];
        seg_blk[tid] = (short)(unc ? -1 : lo);
        positions[b * TT + t] = unc ? (float)t : (float)(t - st);
        if (tid == 0)          s_nlo = lo;  // row range INDEPENDENT of coverage
        if (tid == FRAMES - 1) s_nhi = lo;
    }
    __syncthreads();

    // ---- 3) stage x rows [n_lo, n_hi] (+ zero row) into LDS ----
    const int nlo   = s_nlo;
    const int nrows = s_nhi - nlo + 1;      // <= MAXROWS
    for (int idx = tid; idx < (nrows + 1) * (DD / 4); idx += THREADS) {
        const int r  = idx >> 6;            // row slot; slot nrows = zero row
        const int d4 = (idx & 63) << 2;
        v4f v = (v4f)(0.0f);
        if (r < nrows)
            v = *(const v4f*)(x + (((size_t)b * NN + nlo + r) * DD + d4));
        *(v4f*)(xs + r * DD + d4) = v;
    }
    __syncthreads();

    // ---- 4) out: 128 KiB linear sweep, LDS -> nt store (no vmem loads) ----
    float* oc = outp + ((size_t)b * TT + f0) * DD;
    #pragma unroll 4
    for (int k = 0; k < FRAMES * (DD / 4) / THREADS; ++k) {   // 32 iters
        const int idx = k * THREADS + tid;
        const int f   = idx >> 6;           // frame (uniform per wave)
        const int d4  = (idx & 63) << 2;
        const int sg  = seg_blk[f];
        const int row = (sg < 0) ? nrows : (sg - nlo);
        const v4f v = *(const v4f*)(xs + row * DD + d4);
        __builtin_nontemporal_store(v, (v4f*)(oc + ((size_t)idx << 2)));
    }

    // ---- 5) weight ones: rows sub*8..+7, write 1.0f on [rs, re) ----
    const int n0 = sub * 8;
    for (int r = 0; r < 8; ++r) {
        const int n  = n0 + r;
        const int rs = s_end[n] + (s_cov[n] ? 0 : 1);
        const int re = s_end[n + 1];
        float* wrow = w + (((size_t)b * NN + n) << 13);
        for (int t = rs + tid; t < re; t += THREADS)
            wrow[t] = 1.0f;
    }
}

extern "C" void kernel_launch(void* const* d_in, const int* in_sizes, int n_in,
                              void* d_out, int out_size, void* d_ws, size_t ws_size,
                              hipStream_t stream) {
    const float* x  = (const float*)d_in[0];
    const int* dur  = (const int*)d_in[1];

    // Output layout: positions [B,T] | out [B,T,D] | weights [B,N,T]
    float* pos  = (float*)d_out;
    float* outp = pos + (size_t)BB * TT;
    float* w    = outp + (size_t)BB * TT * DD;

    // Zeros for weights via the rocclr fill path; kernel's one-writes are
    // stream-ordered after it.
    hipMemsetAsync(w, 0, (size_t)BB * NN * TT * sizeof(float), stream);
    fused_kernel<<<BLOCKS, THREADS, 0, stream>>>(x, dur, pos, outp, w);
}